// Round 1
// baseline (1220.556 us; speedup 1.0000x reference)
//
#include <hip/hip_runtime.h>

#define D 96
#define D4 24   // D/4 float4s per row
#define MT 64   // rows per GEMM block
#define KC 64   // k-chunk

// ---- degree: deg[dst] += 1 ----
__global__ void deg_kernel(const int* __restrict__ ei, float* __restrict__ deg, int E) {
    int e = blockIdx.x * 256 + threadIdx.x;
    if (e < E) atomicAdd(&deg[ei[E + e]], 1.0f);
}

// ---- dinv in place: deg <- rsqrt(max(deg,1)) ----
__global__ void dinv_kernel(float* __restrict__ deg, int n) {
    int i = blockIdx.x * 256 + threadIdx.x;
    if (i < n) deg[i] = rsqrtf(fmaxf(deg[i], 1.0f));
}

// ---- per-edge norm + per-node norm-sum s ----
__global__ void norm_kernel(const int* __restrict__ ei, const float* __restrict__ dinv,
                            float* __restrict__ norm, float* __restrict__ s, int E) {
    int e = blockIdx.x * 256 + threadIdx.x;
    if (e < E) {
        int src = ei[e], dst = ei[E + e];
        float nv = dinv[src] * dinv[dst];
        norm[e] = nv;
        atomicAdd(&s[dst], nv);
    }
}

// ---- pre-transpose weights: Vt[k][c], k<96 -> W_lin[c][k], else W_root[c][k-96] ----
__global__ void vt_kernel(const float* __restrict__ Wlin, const float* __restrict__ Wroot,
                          float* __restrict__ Vt) {
    int i = blockIdx.x * 256 + threadIdx.x;
    if (i < 2 * D * D) {
        int k = i / D, c = i % D;
        Vt[i] = (k < D) ? Wlin[c * D + k] : Wroot[c * D + (k - D)];
    }
}

// ---- scatter: y[dst] += norm[e] * x[src], 24 lanes (float4) per edge ----
__global__ void scatter_kernel(const int* __restrict__ ei, const float* __restrict__ x,
                               const float* __restrict__ norm, float* __restrict__ y, int E) {
    int tid = blockIdx.x * 256 + threadIdx.x;
    int e = tid / D4, j = tid % D4;
    if (e < E) {
        int src = ei[e], dst = ei[E + e];
        float nv = norm[e];
        float4 v = ((const float4*)x)[src * D4 + j];
        float* yb = y + (size_t)dst * D + j * 4;
        atomicAdd(yb + 0, nv * v.x);
        atomicAdd(yb + 1, nv * v.y);
        atomicAdd(yb + 2, nv * v.z);
        atomicAdd(yb + 3, nv * v.w);
    }
}

// ---- fused GEMM: out = relu([y|x] @ Vt + s*b_lin + b_root) ----
__global__ __launch_bounds__(384) void gemm_kernel(
    const float* __restrict__ x, const float* __restrict__ y,
    const float* __restrict__ Vt, const float* __restrict__ blin,
    const float* __restrict__ broot, const float* __restrict__ s,
    float* __restrict__ out, int n)
{
    __shared__ float Zs[MT][65];    // pad 65: conflict-free scalar A reads
    __shared__ float Vs[KC][100];   // pad 100: 16B-aligned float4 B reads
    __shared__ float ss[MT];
    __shared__ float bl[D], br[D];

    int t = threadIdx.x;
    int c0 = t % 24;       // col group: cols 4*c0..4*c0+3
    int m0 = t / 24;       // row group: rows 4*m0..4*m0+3
    int r0 = blockIdx.x * MT;

    float acc[4][4] = {};

    if (t < D) { bl[t] = blin[t]; br[t] = broot[t]; }
    if (t < MT) { int r = r0 + t; ss[t] = (r < n) ? s[r] : 0.0f; }

    for (int kc = 0; kc < 2 * D; kc += KC) {
        __syncthreads();
        // stage Z chunk: rows r0..r0+63, k = kc..kc+KC-1 ; k<96 from y, else from x
        for (int task = t; task < MT * (KC / 4); task += 384) {
            int row = task >> 4;       // 0..63
            int kg  = task & 15;       // 0..15
            int k = kc + kg * 4;
            int r = r0 + row;
            float4 v = make_float4(0.f, 0.f, 0.f, 0.f);
            if (r < n) {
                const float* p = (k < D) ? (y + (size_t)r * D + k)
                                         : (x + (size_t)r * D + (k - D));
                v = *(const float4*)p;
            }
            Zs[row][kg * 4 + 0] = v.x;
            Zs[row][kg * 4 + 1] = v.y;
            Zs[row][kg * 4 + 2] = v.z;
            Zs[row][kg * 4 + 3] = v.w;
        }
        // stage V chunk (coalesced read of pre-transposed Vt)
        for (int idx = t; idx < KC * D; idx += 384) {
            int kr = idx / D, c = idx % D;
            Vs[kr][c] = Vt[(size_t)(kc + kr) * D + c];
        }
        __syncthreads();

        #pragma unroll 4
        for (int k = 0; k < KC; ++k) {
            const float4 b = *(const float4*)(&Vs[k][c0 * 4]);
            const float a0 = Zs[m0 * 4 + 0][k];
            const float a1 = Zs[m0 * 4 + 1][k];
            const float a2 = Zs[m0 * 4 + 2][k];
            const float a3 = Zs[m0 * 4 + 3][k];
            acc[0][0] = fmaf(a0, b.x, acc[0][0]);
            acc[0][1] = fmaf(a0, b.y, acc[0][1]);
            acc[0][2] = fmaf(a0, b.z, acc[0][2]);
            acc[0][3] = fmaf(a0, b.w, acc[0][3]);
            acc[1][0] = fmaf(a1, b.x, acc[1][0]);
            acc[1][1] = fmaf(a1, b.y, acc[1][1]);
            acc[1][2] = fmaf(a1, b.z, acc[1][2]);
            acc[1][3] = fmaf(a1, b.w, acc[1][3]);
            acc[2][0] = fmaf(a2, b.x, acc[2][0]);
            acc[2][1] = fmaf(a2, b.y, acc[2][1]);
            acc[2][2] = fmaf(a2, b.z, acc[2][2]);
            acc[2][3] = fmaf(a2, b.w, acc[2][3]);
            acc[3][0] = fmaf(a3, b.x, acc[3][0]);
            acc[3][1] = fmaf(a3, b.y, acc[3][1]);
            acc[3][2] = fmaf(a3, b.z, acc[3][2]);
            acc[3][3] = fmaf(a3, b.w, acc[3][3]);
        }
    }

    // epilogue: + s*b_lin + b_root, relu, store float4
    #pragma unroll
    for (int jr = 0; jr < 4; ++jr) {
        int r = r0 + m0 * 4 + jr;
        if (r < n) {
            float sv = ss[m0 * 4 + jr];
            float4 o;
            o.x = fmaxf(acc[jr][0] + sv * bl[c0 * 4 + 0] + br[c0 * 4 + 0], 0.0f);
            o.y = fmaxf(acc[jr][1] + sv * bl[c0 * 4 + 1] + br[c0 * 4 + 1], 0.0f);
            o.z = fmaxf(acc[jr][2] + sv * bl[c0 * 4 + 2] + br[c0 * 4 + 2], 0.0f);
            o.w = fmaxf(acc[jr][3] + sv * bl[c0 * 4 + 3] + br[c0 * 4 + 3], 0.0f);
            *(float4*)(out + (size_t)r * D + c0 * 4) = o;
        }
    }
}

extern "C" void kernel_launch(void* const* d_in, const int* in_sizes, int n_in,
                              void* d_out, int out_size, void* d_ws, size_t ws_size,
                              hipStream_t stream) {
    const float* x     = (const float*)d_in[0];
    const int*   ei    = (const int*)d_in[1];
    const float* Wlin  = (const float*)d_in[2];
    const float* blin  = (const float*)d_in[3];
    const float* Wroot = (const float*)d_in[4];
    const float* broot = (const float*)d_in[5];
    float* out = (float*)d_out;

    const int n = in_sizes[0] / D;   // 50000
    const int E = in_sizes[1] / 2;   // 800000

    float* w    = (float*)d_ws;
    float* deg  = w;                  // [n]
    float* s    = w + n;              // [n]
    float* norm = w + 2 * n;          // [E]
    float* Vt   = norm + E;           // [2*D*D]
    float* y    = Vt + 2 * D * D;     // [n*D]
    size_t totalF = (size_t)2 * n + E + 2 * D * D + (size_t)n * D;

    hipMemsetAsync(d_ws, 0, totalF * sizeof(float), stream);

    deg_kernel<<<(E + 255) / 256, 256, 0, stream>>>(ei, deg, E);
    dinv_kernel<<<(n + 255) / 256, 256, 0, stream>>>(deg, n);
    norm_kernel<<<(E + 255) / 256, 256, 0, stream>>>(ei, deg, norm, s, E);
    vt_kernel<<<(2 * D * D + 255) / 256, 256, 0, stream>>>(Wlin, Wroot, Vt);
    scatter_kernel<<<(E * D4 + 255) / 256, 256, 0, stream>>>(ei, x, norm, y, E);
    gemm_kernel<<<(n + MT - 1) / MT, 384, 0, stream>>>(x, y, Vt, blin, broot, s, out, n);
}

// Round 2
// 408.523 us; speedup vs baseline: 2.9877x; 2.9877x over previous
//
#include <hip/hip_runtime.h>

#define D 96
#define MT 64   // rows per GEMM block
#define KC 64   // k-chunk

// ---- histogram: degi[dst] += 1 (int atomics) ----
__global__ void hist_kernel(const int* __restrict__ ei, int* __restrict__ degi, int E) {
    int e = blockIdx.x * 256 + threadIdx.x;
    if (e < E) atomicAdd(&degi[ei[E + e]], 1);
}

// ---- single-block exclusive scan: cursor[i] = sum_{k<i} degi[k] ----
__global__ __launch_bounds__(1024) void scan_kernel(const int* __restrict__ degi,
                                                    int* __restrict__ cursor, int n) {
    __shared__ int wsum[16];
    __shared__ int wpre[16];
    __shared__ int carry_s;
    int t = threadIdx.x;
    int lane = t & 63, wid = t >> 6;
    int carry = 0;
    for (int base = 0; base < n; base += 1024) {
        int i = base + t;
        int v = (i < n) ? degi[i] : 0;
        int incl = v;
        #pragma unroll
        for (int d = 1; d < 64; d <<= 1) {
            int u = __shfl_up(incl, d, 64);
            if (lane >= d) incl += u;
        }
        if (lane == 63) wsum[wid] = incl;
        __syncthreads();                       // also protects carry_s rewrite
        if (wid == 0) {
            int wv = (lane < 16) ? wsum[lane] : 0;
            int wincl = wv;
            #pragma unroll
            for (int d = 1; d < 16; d <<= 1) {
                int u = __shfl_up(wincl, d, 64);
                if (lane >= d) wincl += u;
            }
            if (lane < 16) wpre[lane] = wincl - wv;
            if (lane == 15) carry_s = carry + wincl;
        }
        __syncthreads();
        if (i < n) cursor[i] = carry + wpre[wid] + incl - v;
        carry = carry_s;   // all threads; next rewrite is after next iter's first sync
    }
}

// ---- dinv in place over degi buffer: int count -> float rsqrt ----
__global__ void dinv_kernel(int* __restrict__ degi, int n) {
    int i = blockIdx.x * 256 + threadIdx.x;
    if (i < n) {
        int d = degi[i];
        float f = rsqrtf((float)(d > 1 ? d : 1));
        ((float*)degi)[i] = f;
    }
}

// ---- CSR placement: esrc[cursor[dst]++] = src ----
__global__ void place_kernel(const int* __restrict__ ei, int* __restrict__ cursor,
                             int* __restrict__ esrc, int E) {
    int e = blockIdx.x * 256 + threadIdx.x;
    if (e < E) {
        int src = ei[e], dst = ei[E + e];
        int pos = atomicAdd(&cursor[dst], 1);
        esrc[pos] = src;
    }
}

// ---- pre-transpose weights: Vt[k][c] ----
__global__ void vt_kernel(const float* __restrict__ Wlin, const float* __restrict__ Wroot,
                          float* __restrict__ Vt) {
    int i = blockIdx.x * 256 + threadIdx.x;
    if (i < 2 * D * D) {
        int k = i / D, c = i % D;
        Vt[i] = (k < D) ? Wlin[c * D + k] : Wroot[c * D + (k - D)];
    }
}

// ---- gather aggregation: y[dst] = dinv[dst] * sum dinv[src]*x[src]; s likewise ----
// post-place cursor[i] == segment-end of node i; start = cursor[i-1]
__global__ __launch_bounds__(256) void gather_kernel(
    const int* __restrict__ cursor, const int* __restrict__ esrc,
    const float* __restrict__ dinv, const float* __restrict__ x,
    float* __restrict__ y, float* __restrict__ s, int n)
{
    int g = threadIdx.x >> 7;        // node group 0/1
    int c = threadIdx.x & 127;       // component, active c<96
    int node = blockIdx.x * 2 + g;
    if (node >= n) return;
    int start = (node == 0) ? 0 : cursor[node - 1];
    int end   = cursor[node];
    float dn = dinv[node];
    float acc = 0.f, sn = 0.f;
    for (int j = start; j < end; ++j) {
        int src = esrc[j];                       // broadcast load
        float dv = dinv[src];                    // broadcast load
        sn += dv;
        if (c < D) acc += dv * x[(size_t)src * D + c];  // coalesced 384B
    }
    if (c < D) y[(size_t)node * D + c] = dn * acc;
    if (c == 0) s[node] = dn * sn;
}

// ---- fused GEMM: out = relu([y|x] @ Vt + s*b_lin + b_root) ----
__global__ __launch_bounds__(384) void gemm_kernel(
    const float* __restrict__ x, const float* __restrict__ y,
    const float* __restrict__ Vt, const float* __restrict__ blin,
    const float* __restrict__ broot, const float* __restrict__ s,
    float* __restrict__ out, int n)
{
    __shared__ float Zs[MT][65];
    __shared__ float Vs[KC][100];
    __shared__ float ss[MT];
    __shared__ float bl[D], br[D];

    int t = threadIdx.x;
    int c0 = t % 24;
    int m0 = t / 24;
    int r0 = blockIdx.x * MT;

    float acc[4][4] = {};

    if (t < D) { bl[t] = blin[t]; br[t] = broot[t]; }
    if (t < MT) { int r = r0 + t; ss[t] = (r < n) ? s[r] : 0.0f; }

    for (int kc = 0; kc < 2 * D; kc += KC) {
        __syncthreads();
        for (int task = t; task < MT * (KC / 4); task += 384) {
            int row = task >> 4;
            int kg  = task & 15;
            int k = kc + kg * 4;
            int r = r0 + row;
            float4 v = make_float4(0.f, 0.f, 0.f, 0.f);
            if (r < n) {
                const float* p = (k < D) ? (y + (size_t)r * D + k)
                                         : (x + (size_t)r * D + (k - D));
                v = *(const float4*)p;
            }
            Zs[row][kg * 4 + 0] = v.x;
            Zs[row][kg * 4 + 1] = v.y;
            Zs[row][kg * 4 + 2] = v.z;
            Zs[row][kg * 4 + 3] = v.w;
        }
        for (int idx = t; idx < KC * D; idx += 384) {
            int kr = idx / D, c = idx % D;
            Vs[kr][c] = Vt[(size_t)(kc + kr) * D + c];
        }
        __syncthreads();

        #pragma unroll 4
        for (int k = 0; k < KC; ++k) {
            const float4 b = *(const float4*)(&Vs[k][c0 * 4]);
            const float a0 = Zs[m0 * 4 + 0][k];
            const float a1 = Zs[m0 * 4 + 1][k];
            const float a2 = Zs[m0 * 4 + 2][k];
            const float a3 = Zs[m0 * 4 + 3][k];
            acc[0][0] = fmaf(a0, b.x, acc[0][0]);
            acc[0][1] = fmaf(a0, b.y, acc[0][1]);
            acc[0][2] = fmaf(a0, b.z, acc[0][2]);
            acc[0][3] = fmaf(a0, b.w, acc[0][3]);
            acc[1][0] = fmaf(a1, b.x, acc[1][0]);
            acc[1][1] = fmaf(a1, b.y, acc[1][1]);
            acc[1][2] = fmaf(a1, b.z, acc[1][2]);
            acc[1][3] = fmaf(a1, b.w, acc[1][3]);
            acc[2][0] = fmaf(a2, b.x, acc[2][0]);
            acc[2][1] = fmaf(a2, b.y, acc[2][1]);
            acc[2][2] = fmaf(a2, b.z, acc[2][2]);
            acc[2][3] = fmaf(a2, b.w, acc[2][3]);
            acc[3][0] = fmaf(a3, b.x, acc[3][0]);
            acc[3][1] = fmaf(a3, b.y, acc[3][1]);
            acc[3][2] = fmaf(a3, b.z, acc[3][2]);
            acc[3][3] = fmaf(a3, b.w, acc[3][3]);
        }
    }

    #pragma unroll
    for (int jr = 0; jr < 4; ++jr) {
        int r = r0 + m0 * 4 + jr;
        if (r < n) {
            float sv = ss[m0 * 4 + jr];
            float4 o;
            o.x = fmaxf(acc[jr][0] + sv * bl[c0 * 4 + 0] + br[c0 * 4 + 0], 0.0f);
            o.y = fmaxf(acc[jr][1] + sv * bl[c0 * 4 + 1] + br[c0 * 4 + 1], 0.0f);
            o.z = fmaxf(acc[jr][2] + sv * bl[c0 * 4 + 2] + br[c0 * 4 + 2], 0.0f);
            o.w = fmaxf(acc[jr][3] + sv * bl[c0 * 4 + 3] + br[c0 * 4 + 3], 0.0f);
            *(float4*)(out + (size_t)r * D + c0 * 4) = o;
        }
    }
}

extern "C" void kernel_launch(void* const* d_in, const int* in_sizes, int n_in,
                              void* d_out, int out_size, void* d_ws, size_t ws_size,
                              hipStream_t stream) {
    const float* x     = (const float*)d_in[0];
    const int*   ei    = (const int*)d_in[1];
    const float* Wlin  = (const float*)d_in[2];
    const float* blin  = (const float*)d_in[3];
    const float* Wroot = (const float*)d_in[4];
    const float* broot = (const float*)d_in[5];
    float* out = (float*)d_out;

    const int n = in_sizes[0] / D;   // 50000
    const int E = in_sizes[1] / 2;   // 800000

    // workspace layout (4B elements)
    int*   degi   = (int*)d_ws;                 // [n] -> becomes dinv (float) in place
    int*   cursor = degi + n;                   // [n]
    int*   esrc   = cursor + n;                 // [E]
    float* Vt     = (float*)(esrc + E);         // [2*D*D]
    float* s      = Vt + 2 * D * D;             // [n]
    float* y      = s + n;                      // [n*D]

    hipMemsetAsync(degi, 0, (size_t)n * sizeof(int), stream);

    hist_kernel<<<(E + 255) / 256, 256, 0, stream>>>(ei, degi, E);
    scan_kernel<<<1, 1024, 0, stream>>>(degi, cursor, n);
    dinv_kernel<<<(n + 255) / 256, 256, 0, stream>>>(degi, n);
    place_kernel<<<(E + 255) / 256, 256, 0, stream>>>(ei, cursor, esrc, E);
    vt_kernel<<<(2 * D * D + 255) / 256, 256, 0, stream>>>(Wlin, Wroot, Vt);
    gather_kernel<<<(n + 1) / 2, 256, 0, stream>>>(cursor, esrc, (const float*)degi,
                                                   x, y, s, n);
    gemm_kernel<<<(n + MT - 1) / MT, 384, 0, stream>>>(x, y, Vt, blin, broot, s, out, n);
}

// Round 3
// 295.916 us; speedup vs baseline: 4.1247x; 1.3805x over previous
//
#include <hip/hip_runtime.h>

#define D 96
#define MT 64   // rows per GEMM block
#define KC 64   // k-chunk

// ---- histogram: degi[dst] += 1 (int atomics) ----
__global__ void hist_kernel(const int* __restrict__ ei, int* __restrict__ degi, int E) {
    int e = blockIdx.x * 256 + threadIdx.x;
    if (e < E) atomicAdd(&degi[ei[E + e]], 1);
}

// ---- single-block exclusive scan, 4 elems/thread ----
__global__ __launch_bounds__(1024) void scan_kernel(const int* __restrict__ degi,
                                                    int* __restrict__ cursor, int n) {
    __shared__ int wsum[16];
    __shared__ int wpre[16];
    __shared__ int carry_s;
    int t = threadIdx.x;
    int lane = t & 63, wid = t >> 6;
    int carry = 0;
    for (int base = 0; base < n; base += 4096) {
        int i0 = base + t * 4;
        int v0 = 0, v1 = 0, v2 = 0, v3 = 0;
        if (i0 + 3 < n) {
            int4 v = *(const int4*)(degi + i0);
            v0 = v.x; v1 = v.y; v2 = v.z; v3 = v.w;
        } else {
            if (i0     < n) v0 = degi[i0];
            if (i0 + 1 < n) v1 = degi[i0 + 1];
            if (i0 + 2 < n) v2 = degi[i0 + 2];
            if (i0 + 3 < n) v3 = degi[i0 + 3];
        }
        int tsum = v0 + v1 + v2 + v3;
        int incl = tsum;
        #pragma unroll
        for (int d = 1; d < 64; d <<= 1) {
            int u = __shfl_up(incl, d, 64);
            if (lane >= d) incl += u;
        }
        if (lane == 63) wsum[wid] = incl;
        __syncthreads();
        if (wid == 0) {
            int wv = (lane < 16) ? wsum[lane] : 0;
            int wincl = wv;
            #pragma unroll
            for (int d = 1; d < 16; d <<= 1) {
                int u = __shfl_up(wincl, d, 64);
                if (lane >= d) wincl += u;
            }
            if (lane < 16) wpre[lane] = wincl - wv;
            if (lane == 15) carry_s = carry + wincl;
        }
        __syncthreads();
        int pre = carry + wpre[wid] + incl - tsum;
        if (i0     < n) cursor[i0]     = pre;
        if (i0 + 1 < n) cursor[i0 + 1] = pre + v0;
        if (i0 + 2 < n) cursor[i0 + 2] = pre + v0 + v1;
        if (i0 + 3 < n) cursor[i0 + 3] = pre + v0 + v1 + v2;
        __syncthreads();           // protect carry_s before next round's write
        carry = carry_s;
    }
}

// ---- fused: dinv in place over degi + weight transpose Vt ----
__global__ void prep_kernel(int* __restrict__ degi,
                            const float* __restrict__ Wlin, const float* __restrict__ Wroot,
                            float* __restrict__ Vt, int n) {
    int i = blockIdx.x * 256 + threadIdx.x;
    if (i < n) {
        int d = degi[i];
        ((float*)degi)[i] = rsqrtf((float)(d > 1 ? d : 1));
    }
    if (i < 2 * D * D) {
        int k = i / D, c = i % D;
        Vt[i] = (k < D) ? Wlin[c * D + k] : Wroot[c * D + (k - D)];
    }
}

// ---- CSR placement: esrc[cursor[dst]++] = src ----
__global__ void place_kernel(const int* __restrict__ ei, int* __restrict__ cursor,
                             int* __restrict__ esrc, int E) {
    int e = blockIdx.x * 256 + threadIdx.x;
    if (e < E) {
        int src = ei[e], dst = ei[E + e];
        int pos = atomicAdd(&cursor[dst], 1);
        esrc[pos] = src;
    }
}

// ---- gather: y[dst] = dinv[dst]*sum dinv[src]*x[src]; 96 threads/node, 4x unroll ----
__global__ __launch_bounds__(384) void gather_kernel(
    const int* __restrict__ cursor, const int* __restrict__ esrc,
    const float* __restrict__ dinv, const float* __restrict__ x,
    float* __restrict__ y, float* __restrict__ s, int n)
{
    int g = threadIdx.x / 96;        // node group 0..3
    int c = threadIdx.x % 96;        // component (all active)
    int node = blockIdx.x * 4 + g;
    if (node >= n) return;
    int start = (node == 0) ? 0 : cursor[node - 1];
    int end   = cursor[node];
    float dn = dinv[node];
    float acc = 0.f, sn = 0.f;
    int j = start;
    for (; j + 4 <= end; j += 4) {
        int s0 = esrc[j], s1 = esrc[j + 1], s2 = esrc[j + 2], s3 = esrc[j + 3];
        float d0 = dinv[s0], d1 = dinv[s1], d2 = dinv[s2], d3 = dinv[s3];
        float x0 = x[(size_t)s0 * D + c];
        float x1 = x[(size_t)s1 * D + c];
        float x2 = x[(size_t)s2 * D + c];
        float x3 = x[(size_t)s3 * D + c];
        sn += (d0 + d1) + (d2 + d3);
        acc = fmaf(d0, x0, acc);
        acc = fmaf(d1, x1, acc);
        acc = fmaf(d2, x2, acc);
        acc = fmaf(d3, x3, acc);
    }
    for (; j < end; ++j) {
        int s0 = esrc[j];
        float d0 = dinv[s0];
        sn += d0;
        acc = fmaf(d0, x[(size_t)s0 * D + c], acc);
    }
    y[(size_t)node * D + c] = dn * acc;
    if (c == 0) s[node] = dn * sn;
}

// ---- fused GEMM: out = relu([y|x] @ Vt + s*b_lin + b_root) ----
__global__ __launch_bounds__(384) void gemm_kernel(
    const float* __restrict__ x, const float* __restrict__ y,
    const float* __restrict__ Vt, const float* __restrict__ blin,
    const float* __restrict__ broot, const float* __restrict__ s,
    float* __restrict__ out, int n)
{
    __shared__ float Zs[MT][65];
    __shared__ float Vs[KC][100];
    __shared__ float ss[MT];
    __shared__ float bl[D], br[D];

    int t = threadIdx.x;
    int c0 = t % 24;
    int m0 = t / 24;
    int r0 = blockIdx.x * MT;

    float acc[4][4] = {};

    if (t < D) { bl[t] = blin[t]; br[t] = broot[t]; }
    if (t < MT) { int r = r0 + t; ss[t] = (r < n) ? s[r] : 0.0f; }

    for (int kc = 0; kc < 2 * D; kc += KC) {
        __syncthreads();
        for (int task = t; task < MT * (KC / 4); task += 384) {
            int row = task >> 4;
            int kg  = task & 15;
            int k = kc + kg * 4;
            int r = r0 + row;
            float4 v = make_float4(0.f, 0.f, 0.f, 0.f);
            if (r < n) {
                const float* p = (k < D) ? (y + (size_t)r * D + k)
                                         : (x + (size_t)r * D + (k - D));
                v = *(const float4*)p;
            }
            Zs[row][kg * 4 + 0] = v.x;
            Zs[row][kg * 4 + 1] = v.y;
            Zs[row][kg * 4 + 2] = v.z;
            Zs[row][kg * 4 + 3] = v.w;
        }
        for (int idx = t; idx < KC * D; idx += 384) {
            int kr = idx / D, c = idx % D;
            Vs[kr][c] = Vt[(size_t)(kc + kr) * D + c];
        }
        __syncthreads();

        #pragma unroll 4
        for (int k = 0; k < KC; ++k) {
            const float4 b = *(const float4*)(&Vs[k][c0 * 4]);
            const float a0 = Zs[m0 * 4 + 0][k];
            const float a1 = Zs[m0 * 4 + 1][k];
            const float a2 = Zs[m0 * 4 + 2][k];
            const float a3 = Zs[m0 * 4 + 3][k];
            acc[0][0] = fmaf(a0, b.x, acc[0][0]);
            acc[0][1] = fmaf(a0, b.y, acc[0][1]);
            acc[0][2] = fmaf(a0, b.z, acc[0][2]);
            acc[0][3] = fmaf(a0, b.w, acc[0][3]);
            acc[1][0] = fmaf(a1, b.x, acc[1][0]);
            acc[1][1] = fmaf(a1, b.y, acc[1][1]);
            acc[1][2] = fmaf(a1, b.z, acc[1][2]);
            acc[1][3] = fmaf(a1, b.w, acc[1][3]);
            acc[2][0] = fmaf(a2, b.x, acc[2][0]);
            acc[2][1] = fmaf(a2, b.y, acc[2][1]);
            acc[2][2] = fmaf(a2, b.z, acc[2][2]);
            acc[2][3] = fmaf(a2, b.w, acc[2][3]);
            acc[3][0] = fmaf(a3, b.x, acc[3][0]);
            acc[3][1] = fmaf(a3, b.y, acc[3][1]);
            acc[3][2] = fmaf(a3, b.z, acc[3][2]);
            acc[3][3] = fmaf(a3, b.w, acc[3][3]);
        }
    }

    #pragma unroll
    for (int jr = 0; jr < 4; ++jr) {
        int r = r0 + m0 * 4 + jr;
        if (r < n) {
            float sv = ss[m0 * 4 + jr];
            float4 o;
            o.x = fmaxf(acc[jr][0] + sv * bl[c0 * 4 + 0] + br[c0 * 4 + 0], 0.0f);
            o.y = fmaxf(acc[jr][1] + sv * bl[c0 * 4 + 1] + br[c0 * 4 + 1], 0.0f);
            o.z = fmaxf(acc[jr][2] + sv * bl[c0 * 4 + 2] + br[c0 * 4 + 2], 0.0f);
            o.w = fmaxf(acc[jr][3] + sv * bl[c0 * 4 + 3] + br[c0 * 4 + 3], 0.0f);
            *(float4*)(out + (size_t)r * D + c0 * 4) = o;
        }
    }
}

extern "C" void kernel_launch(void* const* d_in, const int* in_sizes, int n_in,
                              void* d_out, int out_size, void* d_ws, size_t ws_size,
                              hipStream_t stream) {
    const float* x     = (const float*)d_in[0];
    const int*   ei    = (const int*)d_in[1];
    const float* Wlin  = (const float*)d_in[2];
    const float* blin  = (const float*)d_in[3];
    const float* Wroot = (const float*)d_in[4];
    const float* broot = (const float*)d_in[5];
    float* out = (float*)d_out;

    const int n = in_sizes[0] / D;   // 50000
    const int E = in_sizes[1] / 2;   // 800000

    int*   degi   = (int*)d_ws;                 // [n] -> becomes dinv (float) in place
    int*   cursor = degi + n;                   // [n]
    int*   esrc   = cursor + n;                 // [E]
    float* Vt     = (float*)(esrc + E);         // [2*D*D]
    float* s      = Vt + 2 * D * D;             // [n]
    float* y      = s + n;                      // [n*D]

    hipMemsetAsync(degi, 0, (size_t)n * sizeof(int), stream);

    hist_kernel<<<(E + 255) / 256, 256, 0, stream>>>(ei, degi, E);
    scan_kernel<<<1, 1024, 0, stream>>>(degi, cursor, n);
    prep_kernel<<<(((n > 2 * D * D) ? n : 2 * D * D) + 255) / 256, 256, 0, stream>>>(
        degi, Wlin, Wroot, Vt, n);
    place_kernel<<<(E + 255) / 256, 256, 0, stream>>>(ei, cursor, esrc, E);
    gather_kernel<<<(n + 3) / 4, 384, 0, stream>>>(cursor, esrc, (const float*)degi,
                                                   x, y, s, n);
    gemm_kernel<<<(n + MT - 1) / MT, 384, 0, stream>>>(x, y, Vt, blin, broot, s, out, n);
}